// Round 11
// baseline (98.989 us; speedup 1.0000x reference)
//
#include <hip/hip_runtime.h>

#define T_LEN 256
#define NGROUP 49          // 49 groups x 8 steps = 392 steps (s = 0..391)

__device__ __forceinline__ float ex2(float x) { return __builtin_amdgcn_exp2f(x); }
__device__ __forceinline__ float rcp1p(float e) { return __builtin_amdgcn_rcpf(1.0f + e); }

// wave_shr:1 (0x138): lane i <- lane i-1 (lane 0 keeps own). VALU pipe.
__device__ __forceinline__ float dpp_wave_shr1(float v) {
    int i = __float_as_int(v);
    return __int_as_float(__builtin_amdgcn_update_dpp(i, i, 0x138, 0xF, 0xF, false));
}
// wave_rol:1 (0x134): lane i <- lane (i+1)%64.
__device__ __forceinline__ float dpp_wave_rol1(float v) {
    int i = __float_as_int(v);
    return __int_as_float(__builtin_amdgcn_update_dpp(i, i, 0x134, 0xF, 0xF, false));
}

// R7 skeleton, G=8 groups, seam delay 10, ramp/steady split.
// TWO waves, 1 layer/lane: cell (l,t) at step s = t + lane + 73*wid.
//  - in-wave handoff: DPP wave_shr:1 at step head (prev-step h). Exact.
//  - cross-wave seam: w0 publishes h to plane0[s&63][lane]; w1 lane0's input
//    at step s is h(63, s-73), produced at step s-10. Prefetched at group top
//    (slots 8g-10..8g-3, all written before the previous barrier; overwrite
//    at +54 steps >> drift <8). Single buffer pk[8].
//  - x: register conveyor (wave_rol:1), 4 chunks, switch at g=8,16,24.
//  - out: conveyor on w1 (inject layer-127 h at lane 63, rotate), one
//    coalesced 64-lane store at k==7 of g=24,32,40,48 (s=199,263,327,391).
//  - validity freeze z:=1 (=> h'==h exactly) only in RAMP groups; STEADY
//    groups (w0: g in [8,31], w1: [17,40]) run freeze-free (all lanes valid).
__global__ __launch_bounds__(128, 1) void gru_stack_wavefront(
    const float* __restrict__ x,
    const float* __restrict__ w_ih,
    const float* __restrict__ w_hh,
    const float* __restrict__ b_ih,
    const float* __restrict__ b_hh,
    float* __restrict__ out)
{
    __shared__ float plane0[64 * 64];     // w0 h history [slot][lane], 16 KiB
    const int tid  = threadIdx.x;         // 0..127 == layer index
    const int lane = tid & 63;
    const int wid  = tid >> 6;

    #pragma unroll
    for (int m = tid; m < 64 * 64; m += 128) plane0[m] = 0.0f;

    const float L1 = -1.4426950408889634f;   // -log2(e)   (sigmoid scale)
    const float L2 = -2.8853900817779268f;   // -2*log2(e) (tanh-as-sigmoid scale)

    const float wi_r = L1 * w_ih[3 * tid + 0], wh_r = L1 * w_hh[3 * tid + 0];
    const float b_r  = L1 * (b_ih[3 * tid + 0] + b_hh[3 * tid + 0]);
    const float wi_z = L1 * w_ih[3 * tid + 1], wh_z = L1 * w_hh[3 * tid + 1];
    const float b_z  = L1 * (b_ih[3 * tid + 1] + b_hh[3 * tid + 1]);
    const float wi_n = L2 * w_ih[3 * tid + 2], bi_n = L2 * b_ih[3 * tid + 2];
    const float wh_n = L2 * w_hh[3 * tid + 2], bh_n = L2 * b_hh[3 * tid + 2];

    float xc0 = x[lane];
    float xc1 = x[lane + 64];
    float xc2 = x[lane + 128];
    float xc3 = x[lane + 192];

    float h = 0.0f;
    float c_r = b_r, c_z = b_z, g_n = bh_n;  // h-dependent precomputes (h=0)

    float pk[8];
    float ov = 0.0f;                  // output conveyor (w1)
    float xq = xc0;                   // x conveyor (w0)

    const bool is_l0 = (lane == 0);
    const bool is_w0 = (wid == 0);
    const bool is_w1 = !is_w0;

    __syncthreads();                  // plane0 init visible

    for (int g = 0; g < NGROUP; ++g) {
        if      (g == 8)  xq = xc1;   // chunk switch at s = 64,128,192
        else if (g == 16) xq = xc2;
        else if (g == 24) xq = xc3;

        if (is_w1) {                  // seam prefetch: consumed this group
            #pragma unroll
            for (int k = 0; k < 8; ++k)
                pk[k] = plane0[((8 * g + k - 10) & 63) * 64 + 63];
        }

        const int tb = 8 * g - lane - 73 * wid;   // t at substep k = tb + k
        const bool steady = is_w0 ? (g >= 8 && g <= 31) : (g >= 17 && g <= 40);

        if (steady) {
            #pragma unroll
            for (int k = 0; k < 8; ++k) {
                float alt = is_w1 ? pk[k] : xq;
                float shifted = dpp_wave_shr1(h);
                float in = is_l0 ? alt : shifted;

                float u_r = fmaf(wi_r, in, c_r);
                float u_z = fmaf(wi_z, in, c_z);
                float bse = fmaf(wi_n, in, bi_n);
                float r = rcp1p(ex2(u_r));
                float z = rcp1p(ex2(u_z));
                float n = fmaf(2.0f, rcp1p(ex2(fmaf(r, g_n, bse))), -1.0f);
                h = fmaf(z, h - n, n);

                c_r = fmaf(wh_r, h, b_r);
                c_z = fmaf(wh_z, h, b_z);
                g_n = fmaf(wh_n, h, bh_n);

                if (is_w0) plane0[((8 * g + k) & 63) * 64 + lane] = h;

                float rot = dpp_wave_rol1(ov);
                ov = (lane == 63) ? h : rot;
                xq = dpp_wave_rol1(xq);

                if (k == 7 && is_w1 && g >= 24 && ((g - 24) & 7) == 0)
                    out[8 * g - 192 + lane] = ov;    // s = 199,263,327,391
            }
        } else {
            #pragma unroll
            for (int k = 0; k < 8; ++k) {
                float alt = is_w1 ? pk[k] : xq;
                float shifted = dpp_wave_shr1(h);
                float in = is_l0 ? alt : shifted;

                float u_r = fmaf(wi_r, in, c_r);
                float u_z = fmaf(wi_z, in, c_z);
                float bse = fmaf(wi_n, in, bi_n);
                float r = rcp1p(ex2(u_r));
                float z = rcp1p(ex2(u_z));
                const bool valid = (unsigned)(tb + k) < (unsigned)T_LEN;
                z = valid ? z : 1.0f;                // freeze: h' == h exactly
                float n = fmaf(2.0f, rcp1p(ex2(fmaf(r, g_n, bse))), -1.0f);
                h = fmaf(z, h - n, n);

                c_r = fmaf(wh_r, h, b_r);
                c_z = fmaf(wh_z, h, b_z);
                g_n = fmaf(wh_n, h, bh_n);

                if (is_w0) plane0[((8 * g + k) & 63) * 64 + lane] = h;

                float rot = dpp_wave_rol1(ov);
                ov = (lane == 63) ? h : rot;
                xq = dpp_wave_rol1(xq);

                if (k == 7 && is_w1 && g >= 24 && ((g - 24) & 7) == 0)
                    out[8 * g - 192 + lane] = ov;    // g=48 store lands here
            }
        }
        __syncthreads();              // bounds wave drift (<8 steps)
    }
}

extern "C" void kernel_launch(void* const* d_in, const int* in_sizes, int n_in,
                              void* d_out, int out_size, void* d_ws, size_t ws_size,
                              hipStream_t stream) {
    const float* x    = (const float*)d_in[0];  // [1,256]
    const float* w_ih = (const float*)d_in[1];  // [128,3,1]
    const float* w_hh = (const float*)d_in[2];  // [128,3,1]
    const float* b_ih = (const float*)d_in[3];  // [128,3]
    const float* b_hh = (const float*)d_in[4];  // [128,3]
    float* out = (float*)d_out;                 // [1,256]

    gru_stack_wavefront<<<1, 128, 0, stream>>>(x, w_ih, w_hh, b_ih, b_hh, out);
}

// Round 12
// 95.035 us; speedup vs baseline: 1.0416x; 1.0416x over previous
//
#include <hip/hip_runtime.h>

#define T_LEN 256
#define NG 26              // 26 groups x 16 steps = 416 steps (need 415: s_max=414)

__device__ __forceinline__ float ex2(float x) { return __builtin_amdgcn_exp2f(x); }
__device__ __forceinline__ float rcp1p(float e) { return __builtin_amdgcn_rcpf(1.0f + e); }

// wave_shr:1 (0x138): lane i <- lane i-1 (lane 0 keeps own). VALU pipe.
__device__ __forceinline__ float dpp_wave_shr1(float v) {
    int i = __float_as_int(v);
    return __int_as_float(__builtin_amdgcn_update_dpp(i, i, 0x138, 0xF, 0xF, false));
}
// wave_rol:1 (0x134): lane i <- lane (i+1)%64.
__device__ __forceinline__ float dpp_wave_rol1(float v) {
    int i = __float_as_int(v);
    return __int_as_float(__builtin_amdgcn_update_dpp(i, i, 0x134, 0xF, 0xF, false));
}

// R7 skeleton (best measured: 225 cyc/step), single change in R12: folded
// h-update. TWO waves, 1 layer/lane. cell (l,t) at step s = t + l + 32*(l>=64).
//  - in-wave handoff: DPP wave_shr:1 (exact, prev-step h).
//  - cross-wave (63->64): wave0 writes ring[0][s&63][lane]; wave1 lane0 needs
//    h(63, s-96), written at slot (s-33)&63. Prefetched ONE GROUP AHEAD:
//    at top of group G, read slots (16G+k-17)&63 (k=0..15) for consumption in
//    group G+1 => >=16 steps (~2500 cyc) of cover. Barrier per 16 steps bounds
//    drift; slots live 64 steps => no overwrite hazard.
//  - output conveyor: layer-127 h injected at lane 63 each step, rotated by
//    wave_rol:1; one coalesced 64-lane store per 64 steps (s=222,286,350,414).
//  - R12 fold: h' = s_n*(2-2z) + (z*h + z-1)  [= (1-z)*(2*s_n-1) + z*h],
//    coefficients two_omz/zh_m computed off the critical chain from z and
//    prev-step h. Chain tail after s_n: 1 fma (was 3 dependent ops).
//  - validity gating off-chain: z:=1 when t invalid => two_omz=0, zh_m=h
//    => h'==h exactly (s_n always finite; ring zero-inited).
//  - x reaches wave0 lane0 via a wave_rol:1 register conveyor (4 chunks).
__global__ __launch_bounds__(128, 1) void gru_stack_wavefront(
    const float* __restrict__ x,
    const float* __restrict__ w_ih,
    const float* __restrict__ w_hh,
    const float* __restrict__ b_ih,
    const float* __restrict__ b_hh,
    float* __restrict__ out)
{
    __shared__ float ring[2 * 64 * 64];   // [wid][slot][lane], 32 KiB
    const int tid  = threadIdx.x;         // 0..127 == layer index
    const int lane = tid & 63;
    const int wid  = tid >> 6;

    #pragma unroll 4
    for (int m = tid; m < 2 * 64 * 64; m += 128) ring[m] = 0.0f;

    const float L1 = -1.4426950408889634f;   // -log2(e)
    const float L2 = -2.8853900817779268f;   // -2*log2(e)

    const float wi_r = L1 * w_ih[3 * tid + 0], wh_r = L1 * w_hh[3 * tid + 0];
    const float b_r  = L1 * (b_ih[3 * tid + 0] + b_hh[3 * tid + 0]);
    const float wi_z = L1 * w_ih[3 * tid + 1], wh_z = L1 * w_hh[3 * tid + 1];
    const float b_z  = L1 * (b_ih[3 * tid + 1] + b_hh[3 * tid + 1]);
    const float wi_n = L2 * w_ih[3 * tid + 2], bi_n = L2 * b_ih[3 * tid + 2];
    const float wh_n = L2 * w_hh[3 * tid + 2], bh_n = L2 * b_hh[3 * tid + 2];

    float xc0 = x[lane];
    float xc1 = x[lane + 64];
    float xc2 = x[lane + 128];
    float xc3 = x[lane + 192];

    float h = 0.0f;
    float c_r = b_r, c_z = b_z, g_n = bh_n;

    float pcur[16], pnext[16];
    #pragma unroll
    for (int k = 0; k < 16; ++k) { pcur[k] = 0.0f; pnext[k] = 0.0f; }

    float ov = 0.0f;                      // output conveyor (wave1)
    float xq = xc0;                       // x conveyor (wave0)
    int t = -lane - 96 * wid - 1;         // ++ at step top -> t = s - lane - 96*wid

    const bool is_l0 = (lane == 0);
    const bool is_w1 = (wid == 1);
    float* ringw = &ring[wid * 4096];     // own plane (unconditional write)

    __syncthreads();                      // ring init visible

    for (int g = 0; g < NG; ++g) {
        if      (g == 4)  xq = xc1;       // chunk switch at s = 64,128,192
        else if (g == 8)  xq = xc2;
        else if (g == 12) xq = xc3;

        if (is_w1) {                      // prefetch NEXT group's boundary vals
            const int base = 16 * g - 17;
            #pragma unroll
            for (int k = 0; k < 16; ++k)
                pnext[k] = ring[((base + k) & 63) * 64 + 63];   // plane 0, broadcast
        }

        const int sb = (16 * g) & 63;     // slot base for this group

        #pragma unroll
        for (int k = 0; k < 16; ++k) {
            ++t;
            const bool valid = (unsigned)t < (unsigned)T_LEN;

            float alt = is_w1 ? pcur[k] : xq;        // ready since last group
            float shifted = dpp_wave_shr1(h);        // chain start
            float in = is_l0 ? alt : shifted;

            float u_r  = fmaf(wi_r, in, c_r);
            float u_z  = fmaf(wi_z, in, c_z);
            float u_n0 = fmaf(wi_n, in, bi_n);
            float r = rcp1p(ex2(u_r));
            float z = rcp1p(ex2(u_z));
            z = valid ? z : 1.0f;                    // freeze: two_omz=0, zh_m=h
            float two_omz = fmaf(-2.0f, z, 2.0f);    // 2*(1-z), off-chain
            float zh_m    = fmaf(z, h, z - 1.0f);    // z*h - (1-z), off-chain
            float s_n = rcp1p(ex2(fmaf(r, g_n, u_n0)));
            h = fmaf(s_n, two_omz, zh_m);            // (1-z)*(2*s_n-1) + z*h

            c_r = fmaf(wh_r, h, b_r);                // off input-critical chain
            c_z = fmaf(wh_z, h, b_z);
            g_n = fmaf(wh_n, h, bh_n);

            ringw[((sb + k) & 63) * 64 + lane] = h;  // publish (fire-and-forget)

            // output conveyor: rotate, inject layer-127 h at lane 63
            float rot = dpp_wave_rol1(ov);
            ov = (lane == 63) ? h : rot;
            xq = dpp_wave_rol1(xq);                  // x conveyor advance

            if (k == 14) {                           // stores at s=222,286,350,414
                if (is_w1 && (g & 3) == 1 && g >= 13)
                    out[16 * g - 208 + lane] = ov;   // coalesced 64-lane store
            }
        }

        if (is_w1) {
            #pragma unroll
            for (int k = 0; k < 16; ++k) pcur[k] = pnext[k];
        }
        __syncthreads();                             // bounds wave drift (<16 steps)
    }
}

extern "C" void kernel_launch(void* const* d_in, const int* in_sizes, int n_in,
                              void* d_out, int out_size, void* d_ws, size_t ws_size,
                              hipStream_t stream) {
    const float* x    = (const float*)d_in[0];  // [1,256]
    const float* w_ih = (const float*)d_in[1];  // [128,3,1]
    const float* w_hh = (const float*)d_in[2];  // [128,3,1]
    const float* b_ih = (const float*)d_in[3];  // [128,3]
    const float* b_hh = (const float*)d_in[4];  // [128,3]
    float* out = (float*)d_out;                 // [1,256]

    gru_stack_wavefront<<<1, 128, 0, stream>>>(x, w_ih, w_hh, b_ih, b_hh, out);
}